// Round 16
// baseline (2748.900 us; speedup 1.0000x reference)
//
#include <hip/hip_runtime.h>
#include <math.h>

constexpr int cB = 128;
constexpr int cC = 9;
constexpr int cT = 512;
constexpr int cM = 64;
constexpr int cDOB = 40;
constexpr int cDM = 360;
constexpr int cD = 376;       // d_model + d_pe
constexpr int cDP = 384;      // K-padded stride for bf16 activations
constexpr int cDH = 94;
constexpr int cNHID = 720;
constexpr int cNHP = 736;     // K-padded FF hidden stride
constexpr float cEPS = 1e-5f;
constexpr float cPI = 3.14159265358979323846f;

typedef __attribute__((ext_vector_type(8))) short short8b;  // 8 bf16
typedef __attribute__((ext_vector_type(4))) float f32x4;
typedef const __attribute__((address_space(1))) short glb_short;
typedef __attribute__((address_space(3))) short lds_short;

__device__ __forceinline__ short f2b(float f) {
  union { float f; unsigned u; } c; c.f = f;
  unsigned r = (c.u + 0x7fffu + ((c.u >> 16) & 1u)) >> 16;  // RNE
  return (short)r;
}
__device__ __forceinline__ float b2f(short h) {
  union { unsigned u; float f; } c; c.u = ((unsigned)(unsigned short)h) << 16;
  return c.f;
}

// ---------------- chirp kernel g = ifft(chirp) ----------------
__global__ void k_chirp(float2* __restrict__ g) {
  int d = threadIdx.x;  // 512 threads
  float re = 0.f, im = 0.f;
  for (int k = 0; k < cT; ++k) {
    int q = (k * k) & 2047;
    int p = (k * d) & 511;
    float th = cPI * ((float)p * (1.0f / 256.0f) - (float)q * (1.0f / 1024.0f));
    float s, c;
    sincosf(th, &s, &c);
    re += c; im += s;
  }
  g[d] = make_float2(re * (1.0f / 512.0f), im * (1.0f / 512.0f));
}

// ---------------- spectral branch ----------------
__global__ __launch_bounds__(512) void k_spectral(
    const float* __restrict__ x, const float* __restrict__ w1r,
    const float* __restrict__ w1i, const float2* __restrict__ g,
    float* __restrict__ outft, float* __restrict__ EF) {
  __shared__ float xc[cC][cT];
  __shared__ float2 gs[cT];
  __shared__ float2 xfr[cC][cM];
  int b = blockIdx.x, tid = threadIdx.x;
  for (int i = tid; i < cC * cT; i += 512)
    xc[i / cT][i % cT] = cosf(x[(size_t)b * cC * cT + i]);
  for (int i = tid; i < cT; i += 512) gs[i] = g[i];
  __syncthreads();
  for (int idx = tid; idx < cC * cM; idx += 512) {
    int c = idx / cM, m = idx % cM;
    float re = 0.f, im = 0.f;
    for (int t = 0; t < cT; ++t) {
      float xv = xc[c][t];
      float2 gv = gs[(m - t) & (cT - 1)];
      re += xv * gv.x; im += xv * gv.y;
    }
    xfr[c][m] = make_float2(re, im);
  }
  __syncthreads();
  for (int idx = tid; idx < cC * cM; idx += 512) {
    int o = idx / cM, m = idx % cM;
    float re = 0.f, im = 0.f;
    #pragma unroll
    for (int i = 0; i < cC; ++i) {
      float2 xv = xfr[i][m];
      float wr = w1r[(i * cC + o) * cM + m];
      float wi = w1i[(i * cC + o) * cM + m];
      re += xv.x * wr - xv.y * wi;
      im += xv.x * wi + xv.y * wr;
    }
    outft[(size_t)(b * cC + o) * cT + m] = re;   // real part only
    EF[(b * cC + o) * (2 * cM) + m] = sqrtf(re * re + im * im);
    EF[(b * cC + o) * (2 * cM) + cM + m] = atan2f(im, re);
  }
  for (int idx = tid; idx < cC * (cT - cM); idx += 512) {
    int o = idx / (cT - cM);
    int r = idx % (cT - cM);
    outft[(size_t)(b * cC + o) * cT + cM + r] = 0.f;
  }
}

// ---------------- conv1d C->1 over feature axis ----------------
__global__ void k_convef(const float* __restrict__ EF, const float* __restrict__ cw,
                         float* __restrict__ efp) {
  int i = blockIdx.x * blockDim.x + threadIdx.x;
  if (i >= cB * 2 * cM) return;
  int b = i / (2 * cM), f = i % (2 * cM);
  float acc = 0.f;
  #pragma unroll
  for (int c = 0; c < cC; ++c) {
    const float* row = EF + (b * cC + c) * (2 * cM);
    if (f > 0) acc += row[f - 1] * cw[c * 3 + 0];
    acc += row[f] * cw[c * 3 + 1];
    if (f < 2 * cM - 1) acc += row[f + 1] * cw[c * 3 + 2];
  }
  efp[i] = acc;
}

// ---------------- batchnorm over batch dim ----------------
__global__ __launch_bounds__(128) void k_bn(const float* __restrict__ in,
    const float* __restrict__ gam, const float* __restrict__ bet,
    float* __restrict__ dst, int F, int stride, int off, int reluAfter) {
  __shared__ float red[128];
  int f = blockIdx.x, bt = threadIdx.x;
  float v = in[(size_t)bt * F + f];
  red[bt] = v; __syncthreads();
  for (int s = 64; s > 0; s >>= 1) { if (bt < s) red[bt] += red[bt + s]; __syncthreads(); }
  float mean = red[0] * (1.0f / 128.0f);
  __syncthreads();
  float d = v - mean;
  red[bt] = d * d; __syncthreads();
  for (int s = 64; s > 0; s >>= 1) { if (bt < s) red[bt] += red[bt + s]; __syncthreads(); }
  float var = red[0] * (1.0f / 128.0f);
  float o = d * rsqrtf(var + cEPS) * gam[f] + bet[f];
  if (reluAfter) o = fmaxf(o, 0.f);
  dst[(size_t)bt * stride + off + f] = o;
}

// ---------------- raindrop branch -> Z fp32 + Zb16 (K-padded) ----------------
__global__ __launch_bounds__(256) void k_raindrop(const float* __restrict__ x,
    const float* __restrict__ Ru, const float* __restrict__ Wg1,
    const float* __restrict__ Wg2, float* __restrict__ Z,
    short* __restrict__ Zb16, int bStart) {
  __shared__ float w1s[cDOB * cDOB], w2s[cDOB * cDOB], rus[cDM], tss[8];
  __shared__ float vsh[256][cDOB];
  int tid = threadIdx.x;
  for (int i = tid; i < cDOB * cDOB; i += 256) { w1s[i] = Wg1[i]; w2s[i] = Wg2[i]; }
  for (int i = tid; i < cDM; i += 256) rus[i] = Ru[i];
  if (tid < 8) tss[tid] = powf(100.0f, (float)tid * (1.0f / 7.0f));
  __syncthreads();
  int token0 = blockIdx.x * 256;
  int token = token0 + tid;
  int bl = token / cT, t = token % cT;
  int bg = bStart + bl;
  float s[cDOB];
  #pragma unroll
  for (int d = 0; d < cDOB; ++d) s[d] = 0.f;
  #pragma unroll
  for (int c = 0; c < cC; ++c) {
    float xv = x[((size_t)bg * cC + c) * cT + t];
    #pragma unroll
    for (int d = 0; d < cDOB; ++d) s[d] += fmaxf(xv * rus[c * cDOB + d], 0.f);
  }
  #pragma unroll
  for (int d = 0; d < cDOB; ++d) s[d] *= (1.0f / 9.0f);
  float u[cDOB];
  #pragma unroll
  for (int e = 0; e < cDOB; ++e) {
    float a = 0.f;
    #pragma unroll
    for (int d = 0; d < cDOB; ++d) a += s[d] * w1s[d * cDOB + e];
    u[e] = fmaxf(a, 0.f);
  }
  #pragma unroll
  for (int e = 0; e < cDOB; ++e) {
    float a = 0.f;
    #pragma unroll
    for (int d = 0; d < cDOB; ++d) a += u[d] * w2s[d * cDOB + e];
    vsh[tid][e] = fmaxf(a, 0.f);
  }
  __syncthreads();
  size_t zbase = (size_t)token0 * cD;
  for (int i = tid; i < 256 * cD; i += 256) {
    int tok = i / cD, col = i % cD;
    float val;
    if (col < cDM) {
      val = vsh[tok][col % cDOB];
    } else {
      int j = col - cDM;
      int tt = (token0 + tok) % cT;
      float st = (float)tt / tss[j & 7];
      val = (j < 8) ? sinf(st) : cosf(st);
    }
    Z[zbase + i] = val;
    Zb16[(size_t)(token0 + tok) * cDP + col] = f2b(val);
  }
  for (int i = tid; i < 256 * 8; i += 256) {
    int tok = i >> 3, c = cD + (i & 7);
    Zb16[(size_t)(token0 + tok) * cDP + c] = 0;
  }
}

// ---------------- transpose+convert: in[K][N] fp32 -> out[N][Kpad] bf16 (zero pad) ----------------
__global__ __launch_bounds__(256) void k_cvtT(const float* __restrict__ in,
    short* __restrict__ out, int K, int N, int Kpad) {
  __shared__ float tile[32][33];
  int kb = blockIdx.x * 32, nb = blockIdx.y * 32;
  int tx = threadIdx.x & 31, ty = threadIdx.x >> 5;  // 32x8
  for (int i = ty; i < 32; i += 8) {
    int k = kb + i, n = nb + tx;
    tile[i][tx] = (k < K && n < N) ? in[(size_t)k * N + n] : 0.f;
  }
  __syncthreads();
  for (int i = ty; i < 32; i += 8) {
    int n = nb + i, k = kb + tx;
    if (n < N && k < Kpad) out[(size_t)n * Kpad + k] = f2b(tile[tx][i]);
  }
}

// ============ GEMM core: A bf16 [M][Kpad], B bf16 [N][Kpad], 128x128 tile, BK=32 ============
// global_load_lds width-16 staging, linear LDS, XOR slot swizzle. Kd multiple of 32.
// XCD-chunked block swizzle (bijective when nwg%8==0).
#define GEMM_CORE(EPILOGUE)                                                       \
  __shared__ __align__(16) short As[128 * 32];                                    \
  __shared__ __align__(16) short Bs[128 * 32];                                    \
  int tid = threadIdx.x;                                                          \
  int nbx = gridDim.x;                                                            \
  int flat = blockIdx.y * nbx + blockIdx.x;                                       \
  int nwg = nbx * gridDim.y;                                                      \
  int swz = ((nwg & 7) == 0) ? ((flat & 7) * (nwg >> 3) + (flat >> 3)) : flat;    \
  int m0 = (swz / nbx) * 128, n0 = (swz % nbx) * 128;                             \
  int w = tid >> 6, l = tid & 63;                                                 \
  int wm = w >> 1, wn = w & 1;                                                    \
  int lr = l & 15, lg = l >> 4;                                                   \
  f32x4 acc[4][4];                                                                \
  _Pragma("unroll") for (int i = 0; i < 4; ++i)                                   \
    _Pragma("unroll") for (int j = 0; j < 4; ++j)                                 \
      _Pragma("unroll") for (int r = 0; r < 4; ++r) acc[i][j][r] = 0.f;           \
  int rbase = w * 32;                                                             \
  int lrow = l >> 2, lslot = l & 3;                                               \
  int nK = Kd >> 5;                                                               \
  for (int ks = 0; ks < nK; ++ks) {                                               \
    int k0 = ks << 5;                                                             \
    _Pragma("unroll") for (int q = 0; q < 2; ++q) {                               \
      int r = rbase + q * 16 + lrow;                                              \
      int cl = lslot ^ ((r >> 1) & 3);                                            \
      __builtin_amdgcn_global_load_lds(                                           \
          (glb_short*)(At + (size_t)(m0 + r) * Kd + k0 + cl * 8),                 \
          (lds_short*)&As[(rbase + q * 16) * 32], 16, 0, 0);                      \
      __builtin_amdgcn_global_load_lds(                                           \
          (glb_short*)(Bt + (size_t)(n0 + r) * Kd + k0 + cl * 8),                 \
          (lds_short*)&Bs[(rbase + q * 16) * 32], 16, 0, 0);                      \
    }                                                                             \
    __syncthreads();                                                              \
    short8b af[4], bf[4];                                                         \
    _Pragma("unroll") for (int i = 0; i < 4; ++i) {                               \
      int row = wm * 64 + i * 16 + lr;                                            \
      int sl = lg ^ ((row >> 1) & 3);                                             \
      af[i] = *(short8b*)&As[row * 32 + sl * 8];                                  \
    }                                                                             \
    _Pragma("unroll") for (int j = 0; j < 4; ++j) {                               \
      int row = wn * 64 + j * 16 + lr;                                            \
      int sl = lg ^ ((row >> 1) & 3);                                             \
      bf[j] = *(short8b*)&Bs[row * 32 + sl * 8];                                  \
    }                                                                             \
    _Pragma("unroll") for (int i = 0; i < 4; ++i)                                 \
      _Pragma("unroll") for (int j = 0; j < 4; ++j)                               \
        acc[i][j] = __builtin_amdgcn_mfma_f32_16x16x32_bf16(af[i], bf[j], acc[i][j], 0, 0, 0); \
    __syncthreads();                                                              \
  }                                                                               \
  _Pragma("unroll") for (int i = 0; i < 4; ++i)                                   \
    _Pragma("unroll") for (int j = 0; j < 4; ++j) {                               \
      int gn = n0 + wn * 64 + j * 16 + lr;                                        \
      if (gn >= Nst) continue;                                                    \
      float bv = (bias && gn < Nc) ? bias[gn] : 0.f;                              \
      int gmb = m0 + wm * 64 + i * 16 + lg * 4;                                   \
      _Pragma("unroll") for (int r = 0; r < 4; ++r) {                             \
        int gm = gmb + r;                                                         \
        if (gm >= Mr) continue;                                                   \
        float vv = acc[i][j][r] + bv;                                             \
        EPILOGUE                                                                  \
      }                                                                           \
    }

// bf16-out GEMM (FF1 -> Hb16, relu); Nst = padded stride, zeros for gn in [Nc,Nst)
__global__ __launch_bounds__(256) void k_gemm_b16(
    const short* __restrict__ At, const short* __restrict__ Bt,
    const float* __restrict__ bias, short* __restrict__ Cm,
    int Mr, int Nc, int Nst, int Kd, int relu) {
  GEMM_CORE({
    if (relu) vv = fmaxf(vv, 0.f);
    Cm[(size_t)gm * Nst + gn] = (gn < Nc) ? f2b(vv) : (short)0;
  })
}

// packed hi/lo bf16-out GEMM (QKV): one u32 = hi | lo<<16 per value; Nst == Nc
__global__ __launch_bounds__(256) void k_gemm_qkv(
    const short* __restrict__ At, const short* __restrict__ Bt,
    const float* __restrict__ bias, unsigned* __restrict__ Cp,
    int Mr, int Nc, int Nst, int Kd) {
  GEMM_CORE({
    short hv = f2b(vv);
    short lv2 = f2b(vv - b2f(hv));
    Cp[(size_t)gm * Nst + gn] =
        ((unsigned)(unsigned short)hv) | (((unsigned)(unsigned short)lv2) << 16);
  })
}

// ============ fused GEMM + residual + LayerNorm ============
// A bf16 [M][Kd], B bf16 [>=376][Kd] (N=376 live, overread rows masked).
// One block = 128 rows x full 384 cols (8 waves, 2x4). Computes Y = A*B^T + bias,
// then Z = LN(Z + Y) per row; writes Z fp32 [M][376] + Zb16 [M][384] (pad zeroed).
__global__ __launch_bounds__(512) void k_gemm_ln(
    const short* __restrict__ At, const short* __restrict__ Bt,
    const float* __restrict__ bias, const float* __restrict__ gam,
    const float* __restrict__ bet, float* __restrict__ Z,
    short* __restrict__ Zb16, int Mr, int Kd) {
  __shared__ __align__(16) short As[128 * 32];
  __shared__ __align__(16) short Bs[384 * 32];
  __shared__ float red[128][4];
  int tid = threadIdx.x;
  int nwg = gridDim.x;
  int flat = blockIdx.x;
  int swz = ((nwg & 7) == 0) ? ((flat & 7) * (nwg >> 3) + (flat >> 3)) : flat;
  int m0 = swz * 128;
  int w = tid >> 6, l = tid & 63;
  int wm = w >> 2, wn = w & 3;        // 2 x 4 wave grid
  int lr = l & 15, lg = l >> 4;
  f32x4 acc[4][6];
  #pragma unroll
  for (int i = 0; i < 4; ++i)
    #pragma unroll
    for (int j = 0; j < 6; ++j)
      #pragma unroll
      for (int r = 0; r < 4; ++r) acc[i][j][r] = 0.f;
  int lrow = l >> 2, lslot = l & 3;
  int nK = Kd >> 5;
  for (int ks = 0; ks < nK; ++ks) {
    int k0 = ks << 5;
    {   // A: wave w stages rows w*16 .. w*16+15
      int r = w * 16 + lrow;
      int cl = lslot ^ ((r >> 1) & 3);
      __builtin_amdgcn_global_load_lds(
          (glb_short*)(At + (size_t)(m0 + r) * Kd + k0 + cl * 8),
          (lds_short*)&As[(w * 16) * 32], 16, 0, 0);
    }
    #pragma unroll
    for (int q = 0; q < 3; ++q) {   // B: 384 rows in 3 rounds
      int r = q * 128 + w * 16 + lrow;
      int cl = lslot ^ ((r >> 1) & 3);
      __builtin_amdgcn_global_load_lds(
          (glb_short*)(Bt + (size_t)r * Kd + k0 + cl * 8),
          (lds_short*)&Bs[(q * 128 + w * 16) * 32], 16, 0, 0);
    }
    __syncthreads();
    short8b af[4], bf[6];
    #pragma unroll
    for (int i = 0; i < 4; ++i) {
      int row = wm * 64 + i * 16 + lr;
      int sl = lg ^ ((row >> 1) & 3);
      af[i] = *(short8b*)&As[row * 32 + sl * 8];
    }
    #pragma unroll
    for (int j = 0; j < 6; ++j) {
      int row = wn * 96 + j * 16 + lr;
      int sl = lg ^ ((row >> 1) & 3);
      bf[j] = *(short8b*)&Bs[row * 32 + sl * 8];
    }
    #pragma unroll
    for (int i = 0; i < 4; ++i)
      #pragma unroll
      for (int j = 0; j < 6; ++j)
        acc[i][j] = __builtin_amdgcn_mfma_f32_16x16x32_bf16(af[i], bf[j], acc[i][j], 0, 0, 0);
    __syncthreads();
  }
  // ---- fused epilogue: Z = LN(Z + Y) ----
  int gnj[6]; float bvj[6], gamj[6], betj[6]; bool vcj[6];
  #pragma unroll
  for (int j = 0; j < 6; ++j) {
    int gn = wn * 96 + j * 16 + lr;
    gnj[j] = gn;
    vcj[j] = (gn < cD);
    bvj[j] = vcj[j] ? bias[gn] : 0.f;
    gamj[j] = vcj[j] ? gam[gn] : 0.f;
    betj[j] = vcj[j] ? bet[gn] : 0.f;
  }
  // pass 1: row sums
  float ps[4][4];
  #pragma unroll
  for (int i = 0; i < 4; ++i)
    #pragma unroll
    for (int r = 0; r < 4; ++r) ps[i][r] = 0.f;
  #pragma unroll
  for (int i = 0; i < 4; ++i)
    #pragma unroll
    for (int r = 0; r < 4; ++r) {
      int gm = m0 + wm * 64 + i * 16 + lg * 4 + r;
      if (gm >= Mr) continue;
      float s = 0.f;
      #pragma unroll
      for (int j = 0; j < 6; ++j)
        if (vcj[j]) s += acc[i][j][r] + bvj[j] + Z[(size_t)gm * cD + gnj[j]];
      ps[i][r] = s;
    }
  #pragma unroll
  for (int i = 0; i < 4; ++i)
    #pragma unroll
    for (int r = 0; r < 4; ++r) {
      float s = ps[i][r];
      #pragma unroll
      for (int off = 8; off > 0; off >>= 1) s += __shfl_xor(s, off, 16);
      ps[i][r] = s;
    }
  if (lr == 0) {
    #pragma unroll
    for (int i = 0; i < 4; ++i)
      #pragma unroll
      for (int r = 0; r < 4; ++r)
        red[wm * 64 + i * 16 + lg * 4 + r][wn] = ps[i][r];
  }
  __syncthreads();
  float mean[4][4];
  #pragma unroll
  for (int i = 0; i < 4; ++i)
    #pragma unroll
    for (int r = 0; r < 4; ++r) {
      int lw = wm * 64 + i * 16 + lg * 4 + r;
      mean[i][r] = (red[lw][0] + red[lw][1] + red[lw][2] + red[lw][3]) / (float)cD;
    }
  __syncthreads();
  // pass 2: row variance (Z re-read is L2-hot)
  #pragma unroll
  for (int i = 0; i < 4; ++i)
    #pragma unroll
    for (int r = 0; r < 4; ++r) {
      int gm = m0 + wm * 64 + i * 16 + lg * 4 + r;
      float s = 0.f;
      if (gm < Mr) {
        #pragma unroll
        for (int j = 0; j < 6; ++j)
          if (vcj[j]) {
            float t = acc[i][j][r] + bvj[j] + Z[(size_t)gm * cD + gnj[j]] - mean[i][r];
            s += t * t;
          }
      }
      ps[i][r] = s;
    }
  #pragma unroll
  for (int i = 0; i < 4; ++i)
    #pragma unroll
    for (int r = 0; r < 4; ++r) {
      float s = ps[i][r];
      #pragma unroll
      for (int off = 8; off > 0; off >>= 1) s += __shfl_xor(s, off, 16);
      ps[i][r] = s;
    }
  if (lr == 0) {
    #pragma unroll
    for (int i = 0; i < 4; ++i)
      #pragma unroll
      for (int r = 0; r < 4; ++r)
        red[wm * 64 + i * 16 + lg * 4 + r][wn] = ps[i][r];
  }
  __syncthreads();
  float inv[4][4];
  #pragma unroll
  for (int i = 0; i < 4; ++i)
    #pragma unroll
    for (int r = 0; r < 4; ++r) {
      int lw = wm * 64 + i * 16 + lg * 4 + r;
      float v = (red[lw][0] + red[lw][1] + red[lw][2] + red[lw][3]) / (float)cD;
      inv[i][r] = rsqrtf(v + cEPS);
    }
  // pass 3: write Z fp32 + Zb16 (pad zero)
  #pragma unroll
  for (int i = 0; i < 4; ++i)
    #pragma unroll
    for (int r = 0; r < 4; ++r) {
      int gm = m0 + wm * 64 + i * 16 + lg * 4 + r;
      if (gm >= Mr) continue;
      #pragma unroll
      for (int j = 0; j < 6; ++j) {
        int gn = gnj[j];
        if (vcj[j]) {
          float t = acc[i][j][r] + bvj[j] + Z[(size_t)gm * cD + gn];
          float res = (t - mean[i][r]) * inv[i][r] * gamj[j] + betj[j];
          Z[(size_t)gm * cD + gn] = res;
          Zb16[(size_t)gm * cDP + gn] = f2b(res);
        } else if (gn < cDP) {
          Zb16[(size_t)gm * cDP + gn] = 0;
        }
      }
    }
}

// ---------------- fp32 tiled GEMM (final projection only) ----------------
__global__ __launch_bounds__(256) void k_gemm(const float* __restrict__ A,
    const float* __restrict__ Bm, const float* __restrict__ bias,
    float* __restrict__ Cm, int Mr, int Nc, int Kd, int relu) {
  __shared__ float As[16][68];
  __shared__ float Bs[16][68];
  int tid = threadIdx.x;
  int tx = tid & 15, ty = tid >> 4;
  int n0 = blockIdx.x * 64, m0 = blockIdx.y * 64;
  float acc[4][4] = {{0.f}};
  for (int k0 = 0; k0 < Kd; k0 += 16) {
    {
      int row = tid >> 2, kq = (tid & 3) << 2;
      int gm = m0 + row, gk = k0 + kq;
      float4 av = make_float4(0.f, 0.f, 0.f, 0.f);
      if (gm < Mr) {
        const float* ap = A + (size_t)gm * Kd + gk;
        if (gk + 3 < Kd) av = *(const float4*)ap;
        else {
          if (gk + 0 < Kd) av.x = ap[0];
          if (gk + 1 < Kd) av.y = ap[1];
          if (gk + 2 < Kd) av.z = ap[2];
        }
      }
      As[kq + 0][row] = av.x; As[kq + 1][row] = av.y;
      As[kq + 2][row] = av.z; As[kq + 3][row] = av.w;
    }
    {
      int kr = tid >> 4, nc = (tid & 15) << 2;
      int gk = k0 + kr, gn = n0 + nc;
      float4 bv = make_float4(0.f, 0.f, 0.f, 0.f);
      if (gk < Kd && gn < Nc) {
        const float* bp = Bm + (size_t)gk * Nc + gn;
        if (gn + 3 < Nc) bv = *(const float4*)bp;
        else {
          bv.x = bp[0];
          if (gn + 1 < Nc) bv.y = bp[1];
          if (gn + 2 < Nc) bv.z = bp[2];
        }
      }
      *(float4*)&Bs[kr][nc] = bv;
    }
    __syncthreads();
    #pragma unroll
    for (int k = 0; k < 16; ++k) {
      float4 a = *(const float4*)&As[k][ty << 2];
      float4 b = *(const float4*)&Bs[k][tx << 2];
      acc[0][0] += a.x * b.x; acc[0][1] += a.x * b.y; acc[0][2] += a.x * b.z; acc[0][3] += a.x * b.w;
      acc[1][0] += a.y * b.x; acc[1][1] += a.y * b.y; acc[1][2] += a.y * b.z; acc[1][3] += a.y * b.w;
      acc[2][0] += a.z * b.x; acc[2][1] += a.z * b.y; acc[2][2] += a.z * b.z; acc[2][3] += a.z * b.w;
      acc[3][0] += a.w * b.x; acc[3][1] += a.w * b.y; acc[3][2] += a.w * b.z; acc[3][3] += a.w * b.w;
    }
    __syncthreads();
  }
  #pragma unroll
  for (int i = 0; i < 4; ++i) {
    int gm = m0 + (ty << 2) + i;
    if (gm >= Mr) continue;
    #pragma unroll
    for (int j = 0; j < 4; ++j) {
      int gn = n0 + (tx << 2) + j;
      if (gn >= Nc) continue;
      float v = acc[i][j] + (bias ? bias[gn] : 0.f);
      if (relu) v = fmaxf(v, 0.f);
      Cm[(size_t)gm * Nc + gn] = v;
    }
  }
}

// ---------------- MFMA flash attention v5: 128-q-row tiles, 8 waves, packed hi/lo ----------------
__global__ __launch_bounds__(512) void k_attn_mfma2(const unsigned* __restrict__ Qp,
    short* __restrict__ ATT16) {
  __shared__ __align__(16) char raw[62464];
  short* kv_h = (short*)raw;                       // [12][64][8]
  short* kv_l = (short*)(raw + 12288);
  int tid = threadIdx.x;
  int w = tid >> 6, l = tid & 63;
  int lr = l & 15, lg = l >> 4;
  short* p_h = (short*)(raw + 24576) + w * 16 * 72;          // 8 waves x [16][72]
  short* p_l = (short*)(raw + 43008) + w * 16 * 72;
  float* fs_w = (float*)(raw + 61440) + w * 16;
  float* il_w = (float*)(raw + 61952) + w * 16;
  int qb = blockIdx.x, h = blockIdx.y, bl = blockIdx.z;
  size_t tokBase = (size_t)bl * cT;
  const float scale = 0.103142125f;   // 1/sqrt(94)
  int qrow = w * 16 + lr;             // 0..127

  short8b qh_s[3], ql_s[3];
  #pragma unroll
  for (int ph = 0; ph < 2; ++ph) {
    size_t base = (tokBase + qb * 128 + ph * 64) * 1128ull + h * cDH;
    for (int task = tid; task < 768; task += 512) {
      int oct = task >> 6, tok = task & 63;
      size_t src = base + (size_t)tok * 1128 + oct * 8;
      uint4 a = *(const uint4*)(Qp + src);
      uint4 b = *(const uint4*)(Qp + src + 4);
      unsigned p[8] = {a.x, a.y, a.z, a.w, b.x, b.y, b.z, b.w};
      short hv[8], lv[8];
      #pragma unroll
      for (int i = 0; i < 8; ++i) { hv[i] = (short)(p[i] & 0xffffu); lv[i] = (short)(p[i] >> 16); }
      if (oct == 11) { hv[6] = 0; hv[7] = 0; lv[6] = 0; lv[7] = 0; }
      int dst = (oct * 64 + (tok ^ (oct & 7))) * 8;
      *(short8b*)&kv_h[dst] = *(short8b*)hv;
      *(short8b*)&kv_l[dst] = *(short8b*)lv;
    }
    __syncthreads();
    if ((w >> 2) == ph) {
      int tokl = qrow & 63;
      #pragma unroll
      for (int s = 0; s < 3; ++s) {
        int o = s * 4 + lg;
        int src = (o * 64 + (tokl ^ (o & 7))) * 8;
        qh_s[s] = *(short8b*)&kv_h[src];
        ql_s[s] = *(short8b*)&kv_l[src];
      }
    }
    __syncthreads();
  }

  f32x4 of[6];
  #pragma unroll
  for (int f = 0; f < 6; ++f)
    #pragma unroll
    for (int r = 0; r < 4; ++r) of[f][r] = 0.f;
  float mrow[4], lrow[4];
  #pragma unroll
  for (int r = 0; r < 4; ++r) { mrow[r] = -1e30f; lrow[r] = 0.f; }

  for (int kt = 0; kt < 8; ++kt) {
    __syncthreads();
    {   // ---- stage K ----
      size_t base = (tokBase + kt * 64) * 1128ull + cD + h * cDH;
      for (int task = tid; task < 768; task += 512) {
        int oct = task >> 6, tok = task & 63;
        size_t src = base + (size_t)tok * 1128 + oct * 8;
        uint4 a = *(const uint4*)(Qp + src);
        uint4 b = *(const uint4*)(Qp + src + 4);
        unsigned p[8] = {a.x, a.y, a.z, a.w, b.x, b.y, b.z, b.w};
        short hv[8], lv[8];
        #pragma unroll
        for (int i = 0; i < 8; ++i) { hv[i] = (short)(p[i] & 0xffffu); lv[i] = (short)(p[i] >> 16); }
        if (oct == 11) { hv[6] = 0; hv[7] = 0; lv[6] = 0; lv[7] = 0; }
        int dst = (oct * 64 + (tok ^ (oct & 7))) * 8;
        *(short8b*)&kv_h[dst] = *(short8b*)hv;
        *(short8b*)&kv_l[dst] = *(short8b*)lv;
      }
    }
    __syncthreads();
    // ---- QK^T (compensated) ----
    f32x4 sf4[4];
    #pragma unroll
    for (int j = 0; j < 4; ++j)
      #pragma unroll
      for (int r = 0; r < 4; ++r) sf4[j][r] = 0.f;
    #pragma unroll
    for (int j = 0; j < 4; ++j) {
      #pragma unroll
      for (int s = 0; s < 3; ++s) {
        int o = s * 4 + lg;
        int src = (o * 64 + ((j * 16 + lr) ^ (o & 7))) * 8;
        short8b bh = *(short8b*)&kv_h[src];
        short8b bl2 = *(short8b*)&kv_l[src];
        sf4[j] = __builtin_amdgcn_mfma_f32_16x16x32_bf16(qh_s[s], bh, sf4[j], 0, 0, 0);
        sf4[j] = __builtin_amdgcn_mfma_f32_16x16x32_bf16(ql_s[s], bh, sf4[j], 0, 0, 0);
        sf4[j] = __builtin_amdgcn_mfma_f32_16x16x32_bf16(qh_s[s], bl2, sf4[j], 0, 0, 0);
      }
    }
    // ---- online softmax; P -> bf16 h/l in LDS ----
    float fscv[4];
    #pragma unroll
    for (int r = 0; r < 4; ++r) {
      float s0 = sf4[0][r] * scale, s1 = sf4[1][r] * scale;
      float s2 = sf4[2][r] * scale, s3 = sf4[3][r] * scale;
      float mx = fmaxf(fmaxf(s0, s1), fmaxf(s2, s3));
      for (int off = 8; off > 0; off >>= 1) mx = fmaxf(mx, __shfl_xor(mx, off, 16));
      float mnew = fmaxf(mrow[r], mx);
      float fsc = __expf(mrow[r] - mnew);
      float p0 = __expf(s0 - mnew), p1 = __expf(s1 - mnew);
      float p2 = __expf(s2 - mnew), p3 = __expf(s3 - mnew);
      float ps = p0 + p1 + p2 + p3;
      for (int off = 8; off > 0; off >>= 1) ps += __shfl_xor(ps, off, 16);
      lrow[r] = lrow[r] * fsc + ps;
      mrow[r] = mnew;
      fscv[r] = fsc;
      int row = (lg * 4 + r) * 72;
      short h0 = f2b(p0);
      p_h[row + 0 * 16 + lr] = h0; p_l[row + 0 * 16 + lr] = f2b(p0 - b2f(h0));
      short h1 = f2b(p1);
      p_h[row + 1 * 16 + lr] = h1; p_l[row + 1 * 16 + lr] = f2b(p1 - b2f(h1));
      short h2 = f2b(p2);
      p_h[row + 2 * 16 + lr] = h2; p_l[row + 2 * 16 + lr] = f2b(p2 - b2f(h2));
      short h3 = f2b(p3);
      p_h[row + 3 * 16 + lr] = h3; p_l[row + 3 * 16 + lr] = f2b(p3 - b2f(h3));
    }
    if (lr == 0) {
      #pragma unroll
      for (int r = 0; r < 4; ++r) fs_w[lg * 4 + r] = fscv[r];
    }
    __syncthreads();   // K reads done; P/fs visible
    {   // ---- stage V^T ----
      size_t base = (tokBase + kt * 64) * 1128ull + 2 * cD + h * cDH;
      for (int task = tid; task < 768; task += 512) {
        int d = task % 96, t8 = task / 96;    // 96 dims x 8 token-octets
        short hv[8], lv[8];
        if (d < cDH) {
          #pragma unroll
          for (int i = 0; i < 8; ++i) {
            unsigned p = Qp[base + (size_t)(t8 * 8 + i) * 1128 + d];
            hv[i] = (short)(p & 0xffffu); lv[i] = (short)(p >> 16);
          }
        } else {
          #pragma unroll
          for (int i = 0; i < 8; ++i) { hv[i] = 0; lv[i] = 0; }
        }
        int dst = d * 64 + ((t8 * 8) ^ ((d & 7) << 3));
        *(short8b*)&kv_h[dst] = *(short8b*)hv;
        *(short8b*)&kv_l[dst] = *(short8b*)lv;
      }
    }
    __syncthreads();   // Vt visible
    float fs = fs_w[lr];
    #pragma unroll
    for (int f = 0; f < 6; ++f)
      #pragma unroll
      for (int r = 0; r < 4; ++r) of[f][r] *= fs;
    // ---- PV: O^T += V^T * P^T (compensated) ----
    #pragma unroll
    for (int s = 0; s < 2; ++s) {
      int pof = lr * 72 + s * 32 + lg * 8;
      short8b ph = *(short8b*)&p_h[pof];
      short8b pl = *(short8b*)&p_l[pof];
      #pragma unroll
      for (int f = 0; f < 6; ++f) {
        int d = f * 16 + lr;
        int vof = d * 64 + ((s * 32 + lg * 8) ^ ((d & 7) << 3));
        short8b vh = *(short8b*)&kv_h[vof];
        short8b vl = *(short8b*)&kv_l[vof];
        of[f] = __builtin_amdgcn_mfma_f32_16x16x32_bf16(vh, ph, of[f], 0, 0, 0);
        of[f] = __builtin_amdgcn_mfma_f32_16x16x32_bf16(vl, ph, of[f], 0, 0, 0);
        of[f] = __builtin_amdgcn_mfma_f32_16x16x32_bf16(vh, pl, of[f], 0, 0, 0);
      }
    }
  }
  // ---- epilogue ----
  if (lr == 0) {
    #pragma unroll
    for (int r = 0; r < 4; ++r) il_w[lg * 4 + r] = 1.0f / lrow[r];
  }
  __syncthreads();
  float il = il_w[lr];
  float* obuf = (float*)raw;   // [128][98] over dead kv+p
  #pragma unroll
  for (int f = 0; f < 6; ++f) {
    #pragma unroll
    for (int r = 0; r < 4; ++r) {
      int d = f * 16 + lg * 4 + r;
      if (d < cDH) obuf[(w * 16 + lr) * 98 + d] = of[f][r] * il;
    }
  }
  __syncthreads();
  for (int idx = tid; idx < 128 * cDH; idx += 512) {
    int q = idx / cDH, d = idx % cDH;
    ATT16[(tokBase + qb * 128 + q) * (size_t)cDP + h * cDH + d] = f2b(obuf[q * 98 + d]);
  }
  if (h == 3) {
    for (int idx = tid; idx < 128 * 8; idx += 512) {
      int q = idx >> 3, c = cD + (idx & 7);
      ATT16[(tokBase + qb * 128 + q) * (size_t)cDP + c] = 0;
    }
  }
}

// ---------------- et[b,d] = mean_t Z[b,t,d] ----------------
__global__ __launch_bounds__(384) void k_meant(const float* __restrict__ Z,
    float* __restrict__ et, int bStart) {
  int bl = blockIdx.x, d = threadIdx.x;
  if (d >= cD) return;
  float s = 0.f;
  for (int t = 0; t < cT; ++t) s += Z[((size_t)bl * cT + t) * cD + d];
  et[(size_t)(bStart + bl) * cD + d] = s * (1.0f / 512.0f);
}

// ---------------- final L2-normalize ----------------
__global__ __launch_bounds__(128) void k_final(const float* __restrict__ fst,
    float* __restrict__ out) {
  __shared__ float red[128];
  int b = blockIdx.x, tid = threadIdx.x;
  float v[5]; float ss = 0.f;
  #pragma unroll
  for (int i = 0; i < 5; ++i) {
    v[i] = fst[(size_t)b * 640 + tid + i * 128];
    ss += v[i] * v[i];
  }
  red[tid] = ss; __syncthreads();
  for (int s = 64; s > 0; s >>= 1) { if (tid < s) red[tid] += red[tid + s]; __syncthreads(); }
  float inv = 1.0f / fmaxf(sqrtf(red[0]), 1e-12f);
  #pragma unroll
  for (int i = 0; i < 5; ++i) out[(size_t)b * 640 + tid + i * 128] = v[i] * inv;
}

extern "C" void kernel_launch(void* const* d_in, const int* in_sizes, int n_in,
                              void* d_out, int out_size, void* d_ws, size_t ws_size,
                              hipStream_t stream) {
  (void)in_sizes; (void)n_in; (void)out_size;
  const float* x     = (const float*)d_in[0];
  const float* w1r   = (const float*)d_in[1];
  const float* w1i   = (const float*)d_in[2];
  const float* convw = (const float*)d_in[3];
  const float* bnfg  = (const float*)d_in[4];
  const float* bnfb  = (const float*)d_in[5];
  const float* Ru    = (const float*)d_in[6];
  const float* Wg1   = (const float*)d_in[7];
  const float* Wg2   = (const float*)d_in[8];
  const float* Wqkv  = (const float*)d_in[9];
  const float* bqkv  = (const float*)d_in[10];
  const float* Wo    = (const float*)d_in[11];
  const float* bo    = (const float*)d_in[12];
  const float* ln1g  = (const float*)d_in[13];
  const float* ln1b  = (const float*)d_in[14];
  const float* W1    = (const float*)d_in[15];
  const float* b1    = (const float*)d_in[16];
  const float* W2    = (const float*)d_in[17];
  const float* b2    = (const float*)d_in[18];
  const float* ln2g  = (const float*)d_in[19];
  const float* ln2b  = (const float*)d_in[20];
  const float* Wp    = (const float*)d_in[21];
  const float* bp    = (const float*)d_in[22];
  const float* bnpg  = (const float*)d_in[23];
  const float* bnpb  = (const float*)d_in[24];

  float* W = (float*)d_ws;
  size_t wsFloats = ws_size / 4;
  float* fst = W;                       //  81920
  float* et  = fst + 81920;             //  48128
  float* etp = et + 48128;              //  65536
  float2* g  = (float2*)(etp + 65536);  //   1024 floats
  float* EF  = (float*)g + 1024;        // 147456
  float* efp = EF + 147456;             //  16384
  short* bfw = (short*)(efp + 16384);
  const size_t oQKV = 0;
  const size_t oWO  = oQKV + (size_t)3 * 1128 * cDP;
  const size_t oW1  = oWO  + (size_t)3 * 376 * cDP;
  const size_t oW2  = oW1  + (size_t)3 * 720 * cDP;
  const size_t bfwShorts = oW2 + (size_t)3 * 376 * cNHP + 1024;  // +tail pad for overreads
  const size_t bfwFloats = (bfwShorts + 1) / 2;
  const size_t fixedFloats = 81920 + 48128 + 65536 + 1024 + 147456 + 16384 + bfwFloats;

  float* outF  = (float*)d_out;
  float* outft = outF + cB * 640;

  if (wsFloats < fixedFloats) return;

  // chunk layout (floats/token): Z 376 | Zb16 192 | QKVp 1128 | ATT16 192 = 1888
  // inside dead QKVp: Hb16 368 floats worth (736 shorts)
  int Bc = 0;
  float* chunk = nullptr;
  for (int c = 128; c >= 1; c >>= 1) {
    size_t need = (size_t)c * cT * 1888 + 64;
    if (fixedFloats + need <= wsFloats) { Bc = c; chunk = W + fixedFloats; break; }
  }
  bool haveChunk = (Bc > 0);

  if (haveChunk) {
    for (int l = 0; l < 3; ++l) {
      k_cvtT<<<dim3(12, 36), 256, 0, stream>>>(Wqkv + (size_t)l * cD * 1128,
          bfw + oQKV + (size_t)l * 1128 * cDP, cD, 1128, cDP);
      k_cvtT<<<dim3(12, 12), 256, 0, stream>>>(Wo + (size_t)l * cD * cD,
          bfw + oWO + (size_t)l * 376 * cDP, cD, cD, cDP);
      k_cvtT<<<dim3(12, 23), 256, 0, stream>>>(W1 + (size_t)l * cD * cNHID,
          bfw + oW1 + (size_t)l * 720 * cDP, cD, cNHID, cDP);
      k_cvtT<<<dim3(23, 12), 256, 0, stream>>>(W2 + (size_t)l * cNHID * cD,
          bfw + oW2 + (size_t)l * 376 * cNHP, cNHID, cD, cNHP);
    }

    float* Zb      = chunk;
    short* Zb16    = (short*)(Zb + (size_t)Bc * cT * cD);
    unsigned* QKVp = (unsigned*)(Zb16 + (size_t)Bc * cT * cDP);
    short* ATT16   = (short*)(QKVp + (size_t)Bc * cT * 1128);
    for (int b0 = 0; b0 < cB; b0 += Bc) {
      int ntok = Bc * cT;
      int mt = (ntok + 127) / 128;
      short* Hb16 = (short*)QKVp;                    // [ntok][736] bf16 (dead QKVp)
      k_raindrop<<<ntok / 256, 256, 0, stream>>>(x, Ru, Wg1, Wg2, Zb, Zb16, b0);
      for (int l = 0; l < 3; ++l) {
        k_gemm_qkv<<<dim3(9, mt), 256, 0, stream>>>(
            Zb16, bfw + oQKV + (size_t)l * 1128 * cDP,
            bqkv + (size_t)l * 1128, QKVp, ntok, 1128, 1128, cDP);
        k_attn_mfma2<<<dim3(4, 4, Bc), 512, 0, stream>>>(QKVp, ATT16);
        k_gemm_ln<<<mt, 512, 0, stream>>>(
            ATT16, bfw + oWO + (size_t)l * 376 * cDP,
            bo + (size_t)l * cD, ln1g + l * cD, ln1b + l * cD,
            Zb, Zb16, ntok, cDP);
        k_gemm_b16<<<dim3(6, mt), 256, 0, stream>>>(
            Zb16, bfw + oW1 + (size_t)l * 720 * cDP,
            b1 + (size_t)l * cNHID, Hb16, ntok, cNHID, cNHP, cDP, 1);
        k_gemm_ln<<<mt, 512, 0, stream>>>(
            Hb16, bfw + oW2 + (size_t)l * 376 * cNHP,
            b2 + (size_t)l * cD, ln2g + l * cD, ln2b + l * cD,
            Zb, Zb16, ntok, cNHP);
      }
      k_meant<<<Bc, 384, 0, stream>>>(Zb, et, b0);
    }
    k_gemm<<<dim3(cT / 64, cB / 64), 256, 0, stream>>>(et, Wp, bp, etp, cB, cT, cD, 1);
  }

  k_chirp<<<1, 512, 0, stream>>>(g);
  k_spectral<<<cB, 512, 0, stream>>>(x, w1r, w1i, g, outft, EF);
  k_convef<<<(cB * 2 * cM + 255) / 256, 256, 0, stream>>>(EF, convw, efp);
  k_bn<<<2 * cM, 128, 0, stream>>>(efp, bnfg, bnfb, fst, 2 * cM, 640, 0, 1);

  if (haveChunk)
    k_bn<<<cT, 128, 0, stream>>>(etp, bnpg, bnpb, fst, cT, 640, 2 * cM, 0);

  k_final<<<cB, 128, 0, stream>>>(fst, outF);
}

// Round 17
// 2649.093 us; speedup vs baseline: 1.0377x; 1.0377x over previous
//
#include <hip/hip_runtime.h>
#include <math.h>

constexpr int cB = 128;
constexpr int cC = 9;
constexpr int cT = 512;
constexpr int cM = 64;
constexpr int cDOB = 40;
constexpr int cDM = 360;
constexpr int cD = 376;       // d_model + d_pe
constexpr int cDP = 384;      // K-padded stride for bf16 activations
constexpr int cDH = 94;
constexpr int cNHID = 720;
constexpr int cNHP = 736;     // K-padded FF hidden stride
constexpr float cEPS = 1e-5f;
constexpr float cPI = 3.14159265358979323846f;

typedef __attribute__((ext_vector_type(8))) short short8b;  // 8 bf16
typedef __attribute__((ext_vector_type(4))) float f32x4;
typedef const __attribute__((address_space(1))) short glb_short;
typedef __attribute__((address_space(3))) short lds_short;

__device__ __forceinline__ short f2b(float f) {
  union { float f; unsigned u; } c; c.f = f;
  unsigned r = (c.u + 0x7fffu + ((c.u >> 16) & 1u)) >> 16;  // RNE
  return (short)r;
}
__device__ __forceinline__ float b2f(short h) {
  union { unsigned u; float f; } c; c.u = ((unsigned)(unsigned short)h) << 16;
  return c.f;
}

// ---------------- chirp kernel g = ifft(chirp) ----------------
__global__ void k_chirp(float2* __restrict__ g) {
  int d = threadIdx.x;  // 512 threads
  float re = 0.f, im = 0.f;
  for (int k = 0; k < cT; ++k) {
    int q = (k * k) & 2047;
    int p = (k * d) & 511;
    float th = cPI * ((float)p * (1.0f / 256.0f) - (float)q * (1.0f / 1024.0f));
    float s, c;
    sincosf(th, &s, &c);
    re += c; im += s;
  }
  g[d] = make_float2(re * (1.0f / 512.0f), im * (1.0f / 512.0f));
}

// ---------------- spectral branch ----------------
__global__ __launch_bounds__(512) void k_spectral(
    const float* __restrict__ x, const float* __restrict__ w1r,
    const float* __restrict__ w1i, const float2* __restrict__ g,
    float* __restrict__ outft, float* __restrict__ EF) {
  __shared__ float xc[cC][cT];
  __shared__ float2 gs[cT];
  __shared__ float2 xfr[cC][cM];
  int b = blockIdx.x, tid = threadIdx.x;
  for (int i = tid; i < cC * cT; i += 512)
    xc[i / cT][i % cT] = cosf(x[(size_t)b * cC * cT + i]);
  for (int i = tid; i < cT; i += 512) gs[i] = g[i];
  __syncthreads();
  for (int idx = tid; idx < cC * cM; idx += 512) {
    int c = idx / cM, m = idx % cM;
    float re = 0.f, im = 0.f;
    for (int t = 0; t < cT; ++t) {
      float xv = xc[c][t];
      float2 gv = gs[(m - t) & (cT - 1)];
      re += xv * gv.x; im += xv * gv.y;
    }
    xfr[c][m] = make_float2(re, im);
  }
  __syncthreads();
  for (int idx = tid; idx < cC * cM; idx += 512) {
    int o = idx / cM, m = idx % cM;
    float re = 0.f, im = 0.f;
    #pragma unroll
    for (int i = 0; i < cC; ++i) {
      float2 xv = xfr[i][m];
      float wr = w1r[(i * cC + o) * cM + m];
      float wi = w1i[(i * cC + o) * cM + m];
      re += xv.x * wr - xv.y * wi;
      im += xv.x * wi + xv.y * wr;
    }
    outft[(size_t)(b * cC + o) * cT + m] = re;   // real part only
    EF[(b * cC + o) * (2 * cM) + m] = sqrtf(re * re + im * im);
    EF[(b * cC + o) * (2 * cM) + cM + m] = atan2f(im, re);
  }
  for (int idx = tid; idx < cC * (cT - cM); idx += 512) {
    int o = idx / (cT - cM);
    int r = idx % (cT - cM);
    outft[(size_t)(b * cC + o) * cT + cM + r] = 0.f;
  }
}

// ---------------- conv1d C->1 over feature axis ----------------
__global__ void k_convef(const float* __restrict__ EF, const float* __restrict__ cw,
                         float* __restrict__ efp) {
  int i = blockIdx.x * blockDim.x + threadIdx.x;
  if (i >= cB * 2 * cM) return;
  int b = i / (2 * cM), f = i % (2 * cM);
  float acc = 0.f;
  #pragma unroll
  for (int c = 0; c < cC; ++c) {
    const float* row = EF + (b * cC + c) * (2 * cM);
    if (f > 0) acc += row[f - 1] * cw[c * 3 + 0];
    acc += row[f] * cw[c * 3 + 1];
    if (f < 2 * cM - 1) acc += row[f + 1] * cw[c * 3 + 2];
  }
  efp[i] = acc;
}

// ---------------- batchnorm over batch dim ----------------
__global__ __launch_bounds__(128) void k_bn(const float* __restrict__ in,
    const float* __restrict__ gam, const float* __restrict__ bet,
    float* __restrict__ dst, int F, int stride, int off, int reluAfter) {
  __shared__ float red[128];
  int f = blockIdx.x, bt = threadIdx.x;
  float v = in[(size_t)bt * F + f];
  red[bt] = v; __syncthreads();
  for (int s = 64; s > 0; s >>= 1) { if (bt < s) red[bt] += red[bt + s]; __syncthreads(); }
  float mean = red[0] * (1.0f / 128.0f);
  __syncthreads();
  float d = v - mean;
  red[bt] = d * d; __syncthreads();
  for (int s = 64; s > 0; s >>= 1) { if (bt < s) red[bt] += red[bt + s]; __syncthreads(); }
  float var = red[0] * (1.0f / 128.0f);
  float o = d * rsqrtf(var + cEPS) * gam[f] + bet[f];
  if (reluAfter) o = fmaxf(o, 0.f);
  dst[(size_t)bt * stride + off + f] = o;
}

// ---------------- raindrop branch -> Z fp32 + Zb16 (K-padded) ----------------
__global__ __launch_bounds__(256) void k_raindrop(const float* __restrict__ x,
    const float* __restrict__ Ru, const float* __restrict__ Wg1,
    const float* __restrict__ Wg2, float* __restrict__ Z,
    short* __restrict__ Zb16, int bStart) {
  __shared__ float w1s[cDOB * cDOB], w2s[cDOB * cDOB], rus[cDM], tss[8];
  __shared__ float vsh[256][cDOB];
  int tid = threadIdx.x;
  for (int i = tid; i < cDOB * cDOB; i += 256) { w1s[i] = Wg1[i]; w2s[i] = Wg2[i]; }
  for (int i = tid; i < cDM; i += 256) rus[i] = Ru[i];
  if (tid < 8) tss[tid] = powf(100.0f, (float)tid * (1.0f / 7.0f));
  __syncthreads();
  int token0 = blockIdx.x * 256;
  int token = token0 + tid;
  int bl = token / cT, t = token % cT;
  int bg = bStart + bl;
  float s[cDOB];
  #pragma unroll
  for (int d = 0; d < cDOB; ++d) s[d] = 0.f;
  #pragma unroll
  for (int c = 0; c < cC; ++c) {
    float xv = x[((size_t)bg * cC + c) * cT + t];
    #pragma unroll
    for (int d = 0; d < cDOB; ++d) s[d] += fmaxf(xv * rus[c * cDOB + d], 0.f);
  }
  #pragma unroll
  for (int d = 0; d < cDOB; ++d) s[d] *= (1.0f / 9.0f);
  float u[cDOB];
  #pragma unroll
  for (int e = 0; e < cDOB; ++e) {
    float a = 0.f;
    #pragma unroll
    for (int d = 0; d < cDOB; ++d) a += s[d] * w1s[d * cDOB + e];
    u[e] = fmaxf(a, 0.f);
  }
  #pragma unroll
  for (int e = 0; e < cDOB; ++e) {
    float a = 0.f;
    #pragma unroll
    for (int d = 0; d < cDOB; ++d) a += u[d] * w2s[d * cDOB + e];
    vsh[tid][e] = fmaxf(a, 0.f);
  }
  __syncthreads();
  size_t zbase = (size_t)token0 * cD;
  for (int i = tid; i < 256 * cD; i += 256) {
    int tok = i / cD, col = i % cD;
    float val;
    if (col < cDM) {
      val = vsh[tok][col % cDOB];
    } else {
      int j = col - cDM;
      int tt = (token0 + tok) % cT;
      float st = (float)tt / tss[j & 7];
      val = (j < 8) ? sinf(st) : cosf(st);
    }
    Z[zbase + i] = val;
    Zb16[(size_t)(token0 + tok) * cDP + col] = f2b(val);
  }
  for (int i = tid; i < 256 * 8; i += 256) {
    int tok = i >> 3, c = cD + (i & 7);
    Zb16[(size_t)(token0 + tok) * cDP + c] = 0;
  }
}

// ---------------- transpose+convert: in[K][N] fp32 -> out[N][Kpad] bf16 (zero pad) ----------------
__global__ __launch_bounds__(256) void k_cvtT(const float* __restrict__ in,
    short* __restrict__ out, int K, int N, int Kpad) {
  __shared__ float tile[32][33];
  int kb = blockIdx.x * 32, nb = blockIdx.y * 32;
  int tx = threadIdx.x & 31, ty = threadIdx.x >> 5;  // 32x8
  for (int i = ty; i < 32; i += 8) {
    int k = kb + i, n = nb + tx;
    tile[i][tx] = (k < K && n < N) ? in[(size_t)k * N + n] : 0.f;
  }
  __syncthreads();
  for (int i = ty; i < 32; i += 8) {
    int n = nb + i, k = kb + tx;
    if (n < N && k < Kpad) out[(size_t)n * Kpad + k] = f2b(tile[tx][i]);
  }
}

// ============ GEMM core: A bf16 [M][Kpad], B bf16 [N][Kpad], 128x128 tile, BK=32 ============
// global_load_lds width-16 staging, linear LDS, XOR slot swizzle (same involution on
// pre-swizzled global source and read). Kd must be multiple of 32 (zero-padded).
// XCD-chunked block swizzle (bijective when nwg%8==0). Bitwise-identical accumulation.
#define GEMM_CORE(EPILOGUE)                                                       \
  __shared__ __align__(16) short As[128 * 32];                                    \
  __shared__ __align__(16) short Bs[128 * 32];                                    \
  int tid = threadIdx.x;                                                          \
  int nbx = gridDim.x;                                                            \
  int flat = blockIdx.y * nbx + blockIdx.x;                                       \
  int nwg = nbx * gridDim.y;                                                      \
  int swz = ((nwg & 7) == 0) ? ((flat & 7) * (nwg >> 3) + (flat >> 3)) : flat;    \
  int m0 = (swz / nbx) * 128, n0 = (swz % nbx) * 128;                             \
  int w = tid >> 6, l = tid & 63;                                                 \
  int wm = w >> 1, wn = w & 1;                                                    \
  int lr = l & 15, lg = l >> 4;                                                   \
  f32x4 acc[4][4];                                                                \
  _Pragma("unroll") for (int i = 0; i < 4; ++i)                                   \
    _Pragma("unroll") for (int j = 0; j < 4; ++j)                                 \
      _Pragma("unroll") for (int r = 0; r < 4; ++r) acc[i][j][r] = 0.f;           \
  int rbase = w * 32;                                                             \
  int lrow = l >> 2, lslot = l & 3;                                               \
  int nK = Kd >> 5;                                                               \
  for (int ks = 0; ks < nK; ++ks) {                                               \
    int k0 = ks << 5;                                                             \
    _Pragma("unroll") for (int q = 0; q < 2; ++q) {                               \
      int r = rbase + q * 16 + lrow;                                              \
      int cl = lslot ^ ((r >> 1) & 3);                                            \
      __builtin_amdgcn_global_load_lds(                                           \
          (glb_short*)(At + (size_t)(m0 + r) * Kd + k0 + cl * 8),                 \
          (lds_short*)&As[(rbase + q * 16) * 32], 16, 0, 0);                      \
      __builtin_amdgcn_global_load_lds(                                           \
          (glb_short*)(Bt + (size_t)(n0 + r) * Kd + k0 + cl * 8),                 \
          (lds_short*)&Bs[(rbase + q * 16) * 32], 16, 0, 0);                      \
    }                                                                             \
    __syncthreads();                                                              \
    short8b af[4], bf[4];                                                         \
    _Pragma("unroll") for (int i = 0; i < 4; ++i) {                               \
      int row = wm * 64 + i * 16 + lr;                                            \
      int sl = lg ^ ((row >> 1) & 3);                                             \
      af[i] = *(short8b*)&As[row * 32 + sl * 8];                                  \
    }                                                                             \
    _Pragma("unroll") for (int j = 0; j < 4; ++j) {                               \
      int row = wn * 64 + j * 16 + lr;                                            \
      int sl = lg ^ ((row >> 1) & 3);                                             \
      bf[j] = *(short8b*)&Bs[row * 32 + sl * 8];                                  \
    }                                                                             \
    _Pragma("unroll") for (int i = 0; i < 4; ++i)                                 \
      _Pragma("unroll") for (int j = 0; j < 4; ++j)                               \
        acc[i][j] = __builtin_amdgcn_mfma_f32_16x16x32_bf16(af[i], bf[j], acc[i][j], 0, 0, 0); \
    __syncthreads();                                                              \
  }                                                                               \
  _Pragma("unroll") for (int i = 0; i < 4; ++i)                                   \
    _Pragma("unroll") for (int j = 0; j < 4; ++j) {                               \
      int gn = n0 + wn * 64 + j * 16 + lr;                                        \
      if (gn >= Nst) continue;                                                    \
      float bv = (bias && gn < Nc) ? bias[gn] : 0.f;                              \
      int gmb = m0 + wm * 64 + i * 16 + lg * 4;                                   \
      _Pragma("unroll") for (int r = 0; r < 4; ++r) {                             \
        int gm = gmb + r;                                                         \
        if (gm >= Mr) continue;                                                   \
        float vv = acc[i][j][r] + bv;                                             \
        EPILOGUE                                                                  \
      }                                                                           \
    }

// fp32-out GEMM (Wo, FF2); Nst == Nc (store stride)
__global__ __launch_bounds__(256) void k_gemm_mfma2(
    const short* __restrict__ At, const short* __restrict__ Bt,
    const float* __restrict__ bias, float* __restrict__ Cm,
    int Mr, int Nc, int Nst, int Kd, int relu) {
  GEMM_CORE({
    if (relu) vv = fmaxf(vv, 0.f);
    Cm[(size_t)gm * Nst + gn] = vv;
  })
}

// bf16-out GEMM (FF1 -> Hb16, relu); Nst = padded stride, zeros for gn in [Nc,Nst)
__global__ __launch_bounds__(256) void k_gemm_b16(
    const short* __restrict__ At, const short* __restrict__ Bt,
    const float* __restrict__ bias, short* __restrict__ Cm,
    int Mr, int Nc, int Nst, int Kd, int relu) {
  GEMM_CORE({
    if (relu) vv = fmaxf(vv, 0.f);
    Cm[(size_t)gm * Nst + gn] = (gn < Nc) ? f2b(vv) : (short)0;
  })
}

// packed hi/lo bf16-out GEMM (QKV): one u32 = hi | lo<<16 per value; Nst == Nc
__global__ __launch_bounds__(256) void k_gemm_qkv(
    const short* __restrict__ At, const short* __restrict__ Bt,
    const float* __restrict__ bias, unsigned* __restrict__ Cp,
    int Mr, int Nc, int Nst, int Kd) {
  GEMM_CORE({
    short hv = f2b(vv);
    short lv2 = f2b(vv - b2f(hv));
    Cp[(size_t)gm * Nst + gn] =
        ((unsigned)(unsigned short)hv) | (((unsigned)(unsigned short)lv2) << 16);
  })
}

// ---------------- fp32 tiled GEMM (final projection only) ----------------
__global__ __launch_bounds__(256) void k_gemm(const float* __restrict__ A,
    const float* __restrict__ Bm, const float* __restrict__ bias,
    float* __restrict__ Cm, int Mr, int Nc, int Kd, int relu) {
  __shared__ float As[16][68];
  __shared__ float Bs[16][68];
  int tid = threadIdx.x;
  int tx = tid & 15, ty = tid >> 4;
  int n0 = blockIdx.x * 64, m0 = blockIdx.y * 64;
  float acc[4][4] = {{0.f}};
  for (int k0 = 0; k0 < Kd; k0 += 16) {
    {
      int row = tid >> 2, kq = (tid & 3) << 2;
      int gm = m0 + row, gk = k0 + kq;
      float4 av = make_float4(0.f, 0.f, 0.f, 0.f);
      if (gm < Mr) {
        const float* ap = A + (size_t)gm * Kd + gk;
        if (gk + 3 < Kd) av = *(const float4*)ap;
        else {
          if (gk + 0 < Kd) av.x = ap[0];
          if (gk + 1 < Kd) av.y = ap[1];
          if (gk + 2 < Kd) av.z = ap[2];
        }
      }
      As[kq + 0][row] = av.x; As[kq + 1][row] = av.y;
      As[kq + 2][row] = av.z; As[kq + 3][row] = av.w;
    }
    {
      int kr = tid >> 4, nc = (tid & 15) << 2;
      int gk = k0 + kr, gn = n0 + nc;
      float4 bv = make_float4(0.f, 0.f, 0.f, 0.f);
      if (gk < Kd && gn < Nc) {
        const float* bp = Bm + (size_t)gk * Nc + gn;
        if (gn + 3 < Nc) bv = *(const float4*)bp;
        else {
          bv.x = bp[0];
          if (gn + 1 < Nc) bv.y = bp[1];
          if (gn + 2 < Nc) bv.z = bp[2];
        }
      }
      *(float4*)&Bs[kr][nc] = bv;
    }
    __syncthreads();
    #pragma unroll
    for (int k = 0; k < 16; ++k) {
      float4 a = *(const float4*)&As[k][ty << 2];
      float4 b = *(const float4*)&Bs[k][tx << 2];
      acc[0][0] += a.x * b.x; acc[0][1] += a.x * b.y; acc[0][2] += a.x * b.z; acc[0][3] += a.x * b.w;
      acc[1][0] += a.y * b.x; acc[1][1] += a.y * b.y; acc[1][2] += a.y * b.z; acc[1][3] += a.y * b.w;
      acc[2][0] += a.z * b.x; acc[2][1] += a.z * b.y; acc[2][2] += a.z * b.z; acc[2][3] += a.z * b.w;
      acc[3][0] += a.w * b.x; acc[3][1] += a.w * b.y; acc[3][2] += a.w * b.z; acc[3][3] += a.w * b.w;
    }
    __syncthreads();
  }
  #pragma unroll
  for (int i = 0; i < 4; ++i) {
    int gm = m0 + (ty << 2) + i;
    if (gm >= Mr) continue;
    #pragma unroll
    for (int j = 0; j < 4; ++j) {
      int gn = n0 + (tx << 2) + j;
      if (gn >= Nc) continue;
      float v = acc[i][j] + (bias ? bias[gn] : 0.f);
      if (relu) v = fmaxf(v, 0.f);
      Cm[(size_t)gm * Nc + gn] = v;
    }
  }
}

// ---------------- MFMA flash attention v5: 128-q-row tiles, 8 waves, packed hi/lo ----------------
// grid (qb=4, h=4, b), 512 threads. K/V staged once per 128 q-rows. ATT16 K-padded out.
__global__ __launch_bounds__(512) void k_attn_mfma2(const unsigned* __restrict__ Qp,
    short* __restrict__ ATT16) {
  __shared__ __align__(16) char raw[62464];
  short* kv_h = (short*)raw;                       // [12][64][8]
  short* kv_l = (short*)(raw + 12288);
  int tid = threadIdx.x;
  int w = tid >> 6, l = tid & 63;
  int lr = l & 15, lg = l >> 4;
  short* p_h = (short*)(raw + 24576) + w * 16 * 72;          // 8 waves x [16][72]
  short* p_l = (short*)(raw + 43008) + w * 16 * 72;
  float* fs_w = (float*)(raw + 61440) + w * 16;
  float* il_w = (float*)(raw + 61952) + w * 16;
  int qb = blockIdx.x, h = blockIdx.y, bl = blockIdx.z;
  size_t tokBase = (size_t)bl * cT;
  const float scale = 0.103142125f;   // 1/sqrt(94)
  int qrow = w * 16 + lr;             // 0..127

  // ---- stage Q in two 64-row phases through kv union; pull per-lane frags ----
  short8b qh_s[3], ql_s[3];
  #pragma unroll
  for (int ph = 0; ph < 2; ++ph) {
    size_t base = (tokBase + qb * 128 + ph * 64) * 1128ull + h * cDH;
    for (int task = tid; task < 768; task += 512) {
      int oct = task >> 6, tok = task & 63;
      size_t src = base + (size_t)tok * 1128 + oct * 8;
      uint4 a = *(const uint4*)(Qp + src);
      uint4 b = *(const uint4*)(Qp + src + 4);
      unsigned p[8] = {a.x, a.y, a.z, a.w, b.x, b.y, b.z, b.w};
      short hv[8], lv[8];
      #pragma unroll
      for (int i = 0; i < 8; ++i) { hv[i] = (short)(p[i] & 0xffffu); lv[i] = (short)(p[i] >> 16); }
      if (oct == 11) { hv[6] = 0; hv[7] = 0; lv[6] = 0; lv[7] = 0; }
      int dst = (oct * 64 + (tok ^ (oct & 7))) * 8;
      *(short8b*)&kv_h[dst] = *(short8b*)hv;
      *(short8b*)&kv_l[dst] = *(short8b*)lv;
    }
    __syncthreads();
    if ((w >> 2) == ph) {
      int tokl = qrow & 63;
      #pragma unroll
      for (int s = 0; s < 3; ++s) {
        int o = s * 4 + lg;
        int src = (o * 64 + (tokl ^ (o & 7))) * 8;
        qh_s[s] = *(short8b*)&kv_h[src];
        ql_s[s] = *(short8b*)&kv_l[src];
      }
    }
    __syncthreads();
  }

  f32x4 of[6];
  #pragma unroll
  for (int f = 0; f < 6; ++f)
    #pragma unroll
    for (int r = 0; r < 4; ++r) of[f][r] = 0.f;
  float mrow[4], lrow[4];
  #pragma unroll
  for (int r = 0; r < 4; ++r) { mrow[r] = -1e30f; lrow[r] = 0.f; }

  for (int kt = 0; kt < 8; ++kt) {
    __syncthreads();
    {   // ---- stage K ----
      size_t base = (tokBase + kt * 64) * 1128ull + cD + h * cDH;
      for (int task = tid; task < 768; task += 512) {
        int oct = task >> 6, tok = task & 63;
        size_t src = base + (size_t)tok * 1128 + oct * 8;
        uint4 a = *(const uint4*)(Qp + src);
        uint4 b = *(const uint4*)(Qp + src + 4);
        unsigned p[8] = {a.x, a.y, a.z, a.w, b.x, b.y, b.z, b.w};
        short hv[8], lv[8];
        #pragma unroll
        for (int i = 0; i < 8; ++i) { hv[i] = (short)(p[i] & 0xffffu); lv[i] = (short)(p[i] >> 16); }
        if (oct == 11) { hv[6] = 0; hv[7] = 0; lv[6] = 0; lv[7] = 0; }
        int dst = (oct * 64 + (tok ^ (oct & 7))) * 8;
        *(short8b*)&kv_h[dst] = *(short8b*)hv;
        *(short8b*)&kv_l[dst] = *(short8b*)lv;
      }
    }
    __syncthreads();
    // ---- QK^T (compensated) ----
    f32x4 sf4[4];
    #pragma unroll
    for (int j = 0; j < 4; ++j)
      #pragma unroll
      for (int r = 0; r < 4; ++r) sf4[j][r] = 0.f;
    #pragma unroll
    for (int j = 0; j < 4; ++j) {
      #pragma unroll
      for (int s = 0; s < 3; ++s) {
        int o = s * 4 + lg;
        int src = (o * 64 + ((j * 16 + lr) ^ (o & 7))) * 8;
        short8b bh = *(short8b*)&kv_h[src];
        short8b bl2 = *(short8b*)&kv_l[src];
        sf4[j] = __builtin_amdgcn_mfma_f32_16x16x32_bf16(qh_s[s], bh, sf4[j], 0, 0, 0);
        sf4[j] = __builtin_amdgcn_mfma_f32_16x16x32_bf16(ql_s[s], bh, sf4[j], 0, 0, 0);
        sf4[j] = __builtin_amdgcn_mfma_f32_16x16x32_bf16(qh_s[s], bl2, sf4[j], 0, 0, 0);
      }
    }
    // ---- online softmax; P -> bf16 h/l in LDS ----
    float fscv[4];
    #pragma unroll
    for (int r = 0; r < 4; ++r) {
      float s0 = sf4[0][r] * scale, s1 = sf4[1][r] * scale;
      float s2 = sf4[2][r] * scale, s3 = sf4[3][r] * scale;
      float mx = fmaxf(fmaxf(s0, s1), fmaxf(s2, s3));
      for (int off = 8; off > 0; off >>= 1) mx = fmaxf(mx, __shfl_xor(mx, off, 16));
      float mnew = fmaxf(mrow[r], mx);
      float fsc = __expf(mrow[r] - mnew);
      float p0 = __expf(s0 - mnew), p1 = __expf(s1 - mnew);
      float p2 = __expf(s2 - mnew), p3 = __expf(s3 - mnew);
      float ps = p0 + p1 + p2 + p3;
      for (int off = 8; off > 0; off >>= 1) ps += __shfl_xor(ps, off, 16);
      lrow[r] = lrow[r] * fsc + ps;
      mrow[r] = mnew;
      fscv[r] = fsc;
      int row = (lg * 4 + r) * 72;
      short h0 = f2b(p0);
      p_h[row + 0 * 16 + lr] = h0; p_l[row + 0 * 16 + lr] = f2b(p0 - b2f(h0));
      short h1 = f2b(p1);
      p_h[row + 1 * 16 + lr] = h1; p_l[row + 1 * 16 + lr] = f2b(p1 - b2f(h1));
      short h2 = f2b(p2);
      p_h[row + 2 * 16 + lr] = h2; p_l[row + 2 * 16 + lr] = f2b(p2 - b2f(h2));
      short h3 = f2b(p3);
      p_h[row + 3 * 16 + lr] = h3; p_l[row + 3 * 16 + lr] = f2b(p3 - b2f(h3));
    }
    if (lr == 0) {
      #pragma unroll
      for (int r = 0; r < 4; ++r) fs_w[lg * 4 + r] = fscv[r];
    }
    __syncthreads();   // K reads done; P/fs visible
    {   // ---- stage V^T: task = (t8, d), coalesced-d loads, b128 LDS writes ----
      size_t base = (tokBase + kt * 64) * 1128ull + 2 * cD + h * cDH;
      for (int task = tid; task < 768; task += 512) {
        int d = task % 96, t8 = task / 96;    // 96 dims x 8 token-octets
        short hv[8], lv[8];
        if (d < cDH) {
          #pragma unroll
          for (int i = 0; i < 8; ++i) {
            unsigned p = Qp[base + (size_t)(t8 * 8 + i) * 1128 + d];
            hv[i] = (short)(p & 0xffffu); lv[i] = (short)(p >> 16);
          }
        } else {
          #pragma unroll
          for (int i = 0; i < 8; ++i) { hv[i] = 0; lv[i] = 0; }
        }
        int dst = d * 64 + ((t8 * 8) ^ ((d & 7) << 3));
        *(short8b*)&kv_h[dst] = *(short8b*)hv;
        *(short8b*)&kv_l[dst] = *(short8b*)lv;
      }
    }
    __syncthreads();   // Vt visible
    float fs = fs_w[lr];
    #pragma unroll
    for (int f = 0; f < 6; ++f)
      #pragma unroll
      for (int r = 0; r < 4; ++r) of[f][r] *= fs;
    // ---- PV: O^T += V^T * P^T (compensated) ----
    #pragma unroll
    for (int s = 0; s < 2; ++s) {
      int pof = lr * 72 + s * 32 + lg * 8;
      short8b ph = *(short8b*)&p_h[pof];
      short8b pl = *(short8b*)&p_l[pof];
      #pragma unroll
      for (int f = 0; f < 6; ++f) {
        int d = f * 16 + lr;
        int vof = d * 64 + ((s * 32 + lg * 8) ^ ((d & 7) << 3));
        short8b vh = *(short8b*)&kv_h[vof];
        short8b vl = *(short8b*)&kv_l[vof];
        of[f] = __builtin_amdgcn_mfma_f32_16x16x32_bf16(vh, ph, of[f], 0, 0, 0);
        of[f] = __builtin_amdgcn_mfma_f32_16x16x32_bf16(vl, ph, of[f], 0, 0, 0);
        of[f] = __builtin_amdgcn_mfma_f32_16x16x32_bf16(vh, pl, of[f], 0, 0, 0);
      }
    }
  }
  // ---- epilogue ----
  if (lr == 0) {
    #pragma unroll
    for (int r = 0; r < 4; ++r) il_w[lg * 4 + r] = 1.0f / lrow[r];
  }
  __syncthreads();
  float il = il_w[lr];
  float* obuf = (float*)raw;   // [128][98] = 50176B over dead kv+p
  #pragma unroll
  for (int f = 0; f < 6; ++f) {
    #pragma unroll
    for (int r = 0; r < 4; ++r) {
      int d = f * 16 + lg * 4 + r;
      if (d < cDH) obuf[(w * 16 + lr) * 98 + d] = of[f][r] * il;
    }
  }
  __syncthreads();
  for (int idx = tid; idx < 128 * cDH; idx += 512) {
    int q = idx / cDH, d = idx % cDH;
    ATT16[(tokBase + qb * 128 + q) * (size_t)cDP + h * cDH + d] = f2b(obuf[q * 98 + d]);
  }
  if (h == 3) {
    for (int idx = tid; idx < 128 * 8; idx += 512) {
      int q = idx >> 3, c = cD + (idx & 7);
      ATT16[(tokBase + qb * 128 + q) * (size_t)cDP + c] = 0;
    }
  }
}

// ---------------- z = LN(z + y), wave-per-token, emit fp32 + bf16 shadow (K-padded) ----------------
__global__ __launch_bounds__(256) void k_addln(float* __restrict__ Z,
    const float* __restrict__ Y, const float* __restrict__ gam,
    const float* __restrict__ bet, short* __restrict__ Zb16) {
  int wid = threadIdx.x >> 6, lane = threadIdx.x & 63;
  size_t token = (size_t)blockIdx.x * 4 + wid;
  size_t base = token * cD;
  size_t b16 = token * cDP;
  float v[6];
  float sum = 0.f;
  #pragma unroll
  for (int j = 0; j < 6; ++j) {
    int c = lane + j * 64;
    float t = 0.f;
    if (c < cD) t = Z[base + c] + Y[base + c];
    v[j] = t; sum += t;
  }
  #pragma unroll
  for (int off = 32; off > 0; off >>= 1) sum += __shfl_xor(sum, off, 64);
  float mean = sum / (float)cD;
  float vs = 0.f;
  #pragma unroll
  for (int j = 0; j < 6; ++j) {
    int c = lane + j * 64;
    if (c < cD) { float d = v[j] - mean; vs += d * d; }
  }
  #pragma unroll
  for (int off = 32; off > 0; off >>= 1) vs += __shfl_xor(vs, off, 64);
  float inv = rsqrtf(vs / (float)cD + cEPS);
  #pragma unroll
  for (int j = 0; j < 6; ++j) {
    int c = lane + j * 64;
    if (c < cD) {
      float res = (v[j] - mean) * inv * gam[c] + bet[c];
      Z[base + c] = res;
      Zb16[b16 + c] = f2b(res);
    } else if (c < cDP) {
      Zb16[b16 + c] = 0;
    }
  }
}

// ---------------- et[b,d] = mean_t Z[b,t,d] ----------------
__global__ __launch_bounds__(384) void k_meant(const float* __restrict__ Z,
    float* __restrict__ et, int bStart) {
  int bl = blockIdx.x, d = threadIdx.x;
  if (d >= cD) return;
  float s = 0.f;
  for (int t = 0; t < cT; ++t) s += Z[((size_t)bl * cT + t) * cD + d];
  et[(size_t)(bStart + bl) * cD + d] = s * (1.0f / 512.0f);
}

// ---------------- final L2-normalize ----------------
__global__ __launch_bounds__(128) void k_final(const float* __restrict__ fst,
    float* __restrict__ out) {
  __shared__ float red[128];
  int b = blockIdx.x, tid = threadIdx.x;
  float v[5]; float ss = 0.f;
  #pragma unroll
  for (int i = 0; i < 5; ++i) {
    v[i] = fst[(size_t)b * 640 + tid + i * 128];
    ss += v[i] * v[i];
  }
  red[tid] = ss; __syncthreads();
  for (int s = 64; s > 0; s >>= 1) { if (tid < s) red[tid] += red[tid + s]; __syncthreads(); }
  float inv = 1.0f / fmaxf(sqrtf(red[0]), 1e-12f);
  #pragma unroll
  for (int i = 0; i < 5; ++i) out[(size_t)b * 640 + tid + i * 128] = v[i] * inv;
}

extern "C" void kernel_launch(void* const* d_in, const int* in_sizes, int n_in,
                              void* d_out, int out_size, void* d_ws, size_t ws_size,
                              hipStream_t stream) {
  (void)in_sizes; (void)n_in; (void)out_size;
  const float* x     = (const float*)d_in[0];
  const float* w1r   = (const float*)d_in[1];
  const float* w1i   = (const float*)d_in[2];
  const float* convw = (const float*)d_in[3];
  const float* bnfg  = (const float*)d_in[4];
  const float* bnfb  = (const float*)d_in[5];
  const float* Ru    = (const float*)d_in[6];
  const float* Wg1   = (const float*)d_in[7];
  const float* Wg2   = (const float*)d_in[8];
  const float* Wqkv  = (const float*)d_in[9];
  const float* bqkv  = (const float*)d_in[10];
  const float* Wo    = (const float*)d_in[11];
  const float* bo    = (const float*)d_in[12];
  const float* ln1g  = (const float*)d_in[13];
  const float* ln1b  = (const float*)d_in[14];
  const float* W1    = (const float*)d_in[15];
  const float* b1    = (const float*)d_in[16];
  const float* W2    = (const float*)d_in[17];
  const float* b2    = (const float*)d_in[18];
  const float* ln2g  = (const float*)d_in[19];
  const float* ln2b  = (const float*)d_in[20];
  const float* Wp    = (const float*)d_in[21];
  const float* bp    = (const float*)d_in[22];
  const float* bnpg  = (const float*)d_in[23];
  const float* bnpb  = (const float*)d_in[24];

  float* W = (float*)d_ws;
  size_t wsFloats = ws_size / 4;
  float* fst = W;                       //  81920
  float* et  = fst + 81920;             //  48128
  float* etp = et + 48128;              //  65536
  float2* g  = (float2*)(etp + 65536);  //   1024 floats
  float* EF  = (float*)g + 1024;        // 147456
  float* efp = EF + 147456;             //  16384
  short* bfw = (short*)(efp + 16384);
  // padded bf16 weights: 3*(1128*384 + 376*384 + 720*384 + 376*736) shorts
  const size_t oQKV = 0;
  const size_t oWO  = oQKV + (size_t)3 * 1128 * cDP;
  const size_t oW1  = oWO  + (size_t)3 * 376 * cDP;
  const size_t oW2  = oW1  + (size_t)3 * 720 * cDP;
  const size_t bfwShorts = oW2 + (size_t)3 * 376 * cNHP;
  const size_t bfwFloats = (bfwShorts + 1) / 2;
  const size_t fixedFloats = 81920 + 48128 + 65536 + 1024 + 147456 + 16384 + bfwFloats;

  float* outF  = (float*)d_out;
  float* outft = outF + cB * 640;

  if (wsFloats < fixedFloats) return;

  // chunk layout (floats/token): Z 376 | Zb16 192 | QKVp 1128 | ATT16 192 = 1888
  // inside dead QKVp: Hb16 368 + WoOut 376 + FF2out 376 = 1120 <= 1128
  int Bc = 0;
  float* chunk = nullptr;
  for (int c = 128; c >= 1; c >>= 1) {
    size_t need = (size_t)c * cT * 1888 + 64;
    if (fixedFloats + need <= wsFloats) { Bc = c; chunk = W + fixedFloats; break; }
  }
  bool haveChunk = (Bc > 0);

  if (haveChunk) {
    for (int l = 0; l < 3; ++l) {
      k_cvtT<<<dim3(12, 36), 256, 0, stream>>>(Wqkv + (size_t)l * cD * 1128,
          bfw + oQKV + (size_t)l * 1128 * cDP, cD, 1128, cDP);
      k_cvtT<<<dim3(12, 12), 256, 0, stream>>>(Wo + (size_t)l * cD * cD,
          bfw + oWO + (size_t)l * 376 * cDP, cD, cD, cDP);
      k_cvtT<<<dim3(12, 23), 256, 0, stream>>>(W1 + (size_t)l * cD * cNHID,
          bfw + oW1 + (size_t)l * 720 * cDP, cD, cNHID, cDP);
      k_cvtT<<<dim3(23, 12), 256, 0, stream>>>(W2 + (size_t)l * cNHID * cD,
          bfw + oW2 + (size_t)l * 376 * cNHP, cNHID, cD, cNHP);
    }

    float* Zb      = chunk;
    short* Zb16    = (short*)(Zb + (size_t)Bc * cT * cD);
    unsigned* QKVp = (unsigned*)(Zb16 + (size_t)Bc * cT * cDP);
    short* ATT16   = (short*)(QKVp + (size_t)Bc * cT * 1128);
    for (int b0 = 0; b0 < cB; b0 += Bc) {
      int ntok = Bc * cT;
      int mt = (ntok + 127) / 128;
      short* Hb16  = (short*)QKVp;                    // [ntok][736] bf16
      float* WoOut = (float*)(Hb16 + (size_t)ntok * cNHP);  // [ntok][376] fp32
      float* FF2o  = WoOut + (size_t)ntok * 376;            // [ntok][376] fp32
      k_raindrop<<<ntok / 256, 256, 0, stream>>>(x, Ru, Wg1, Wg2, Zb, Zb16, b0);
      for (int l = 0; l < 3; ++l) {
        k_gemm_qkv<<<dim3(9, mt), 256, 0, stream>>>(
            Zb16, bfw + oQKV + (size_t)l * 1128 * cDP,
            bqkv + (size_t)l * 1128, QKVp, ntok, 1128, 1128, cDP);
        k_attn_mfma2<<<dim3(4, 4, Bc), 512, 0, stream>>>(QKVp, ATT16);
        k_gemm_mfma2<<<dim3(3, mt), 256, 0, stream>>>(
            ATT16, bfw + oWO + (size_t)l * 376 * cDP,
            bo + (size_t)l * cD, WoOut, ntok, cD, cD, cDP, 0);
        k_addln<<<ntok / 4, 256, 0, stream>>>(Zb, WoOut, ln1g + l * cD, ln1b + l * cD, Zb16);
        k_gemm_b16<<<dim3(6, mt), 256, 0, stream>>>(
            Zb16, bfw + oW1 + (size_t)l * 720 * cDP,
            b1 + (size_t)l * cNHID, Hb16, ntok, cNHID, cNHP, cDP, 1);
        k_gemm_mfma2<<<dim3(3, mt), 256, 0, stream>>>(
            Hb16, bfw + oW2 + (size_t)l * 376 * cNHP,
            b2 + (size_t)l * cD, FF2o, ntok, cD, cD, cNHP, 0);
        k_addln<<<ntok / 4, 256, 0, stream>>>(Zb, FF2o, ln2g + l * cD, ln2b + l * cD, Zb16);
      }
      k_meant<<<Bc, 384, 0, stream>>>(Zb, et, b0);
    }
    k_gemm<<<dim3(cT / 64, cB / 64), 256, 0, stream>>>(et, Wp, bp, etp, cB, cT, cD, 1);
  }

  k_chirp<<<1, 512, 0, stream>>>(g);
  k_spectral<<<cB, 512, 0, stream>>>(x, w1r, w1i, g, outft, EF);
  k_convef<<<(cB * 2 * cM + 255) / 256, 256, 0, stream>>>(EF, convw, efp);
  k_bn<<<2 * cM, 128, 0, stream>>>(efp, bnfg, bnfb, fst, 2 * cM, 640, 0, 1);

  if (haveChunk)
    k_bn<<<cT, 128, 0, stream>>>(etp, bnpg, bnpb, fst, cT, 640, 2 * cM, 0);

  k_final<<<cB, 128, 0, stream>>>(fst, outF);
}